// Round 2
// baseline (20544.305 us; speedup 1.0000x reference)
//
#include <hip/hip_runtime.h>
#include <hip/hip_bf16.h>
#include <stdint.h>

// LSTM bidirectional 2-layer, T=512 B=64 D=H=512.
// Plan: prep(cast+bias+init) -> gemm_xg(L0) -> rec(L0) -> gemm_xg(L1) -> rec(L1).
// rec: 256 single-wave WGs, flag-synced per step (batch-independent groups of 32).
// R2: all-fp16 datapath (4x smaller rounding than bf16, same MFMA rate);
//     bias applied in fp32 inside rec (stored xg is zero-mean -> smaller ulp).

typedef __attribute__((ext_vector_type(8))) _Float16 half8;
typedef __attribute__((ext_vector_type(4))) float f32x4;

__device__ __forceinline__ unsigned short f2h(float f) {
    union { _Float16 h; unsigned short u; } c; c.h = (_Float16)f; return c.u;
}
__device__ __forceinline__ float h2f(unsigned short u) {
    union { _Float16 h; unsigned short u; } c; c.u = u; return (float)c.h;
}

// ---------------- prep: casts, bias sums, state init ----------------
__global__ __launch_bounds__(256) void prep_kernel(
    const float* __restrict__ x,
    const float* __restrict__ w0f, const float* __restrict__ w0b,
    const float* __restrict__ w1f, const float* __restrict__ w1b,
    const float* __restrict__ bi0f, const float* __restrict__ bh0f,
    const float* __restrict__ bi0b, const float* __restrict__ bh0b,
    const float* __restrict__ bi1f, const float* __restrict__ bh1f,
    const float* __restrict__ bi1b, const float* __restrict__ bh1b,
    unsigned short* __restrict__ xh,
    unsigned short* __restrict__ wihh,
    float* __restrict__ bias,
    uint32_t* __restrict__ hbufz,
    int* __restrict__ flags)
{
    const long total = 5802496L;   // units of 16B quads (mostly)
    long stride = (long)gridDim.x * blockDim.x;
    for (long i = (long)blockIdx.x * blockDim.x + threadIdx.x; i < total; i += stride) {
        if (i < 4194304L) {                       // x: fp32 -> fp16 (16.78M elems)
            float4 v = ((const float4*)x)[i];
            ushort4 o; o.x=f2h(v.x); o.y=f2h(v.y); o.z=f2h(v.z); o.w=f2h(v.w);
            ((ushort4*)xh)[i] = o;
        } else if (i < 5767168L) {                // w_ih casts: [w0f][w0b][w1f][w1b]
            long j = i - 4194304L;
            const float* src; long sq;
            if (j < 262144L)       { src = w0f; sq = j;            }
            else if (j < 524288L)  { src = w0b; sq = j - 262144L;  }
            else if (j < 1048576L) { src = w1f; sq = j - 524288L;  }
            else                   { src = w1b; sq = j - 1048576L; }
            float4 v = ((const float4*)src)[sq];
            ushort4 o; o.x=f2h(v.x); o.y=f2h(v.y); o.z=f2h(v.z); o.w=f2h(v.w);
            ((ushort4*)wihh)[j] = o;
        } else if (i < 5769216L) {                // bias sums: b_ih + b_hh, 4 x 2048 fp32
            long j = i - 5767168L;                // 0..2047 quads
            int ld = (int)(j >> 9);
            long cq = j & 511L;
            const float* bi = ld==0?bi0f: ld==1?bi0b: ld==2?bi1f:bi1b;
            const float* bh = ld==0?bh0f: ld==1?bh0b: ld==2?bh1f:bh1b;
            float4 a = ((const float4*)bi)[cq];
            float4 b = ((const float4*)bh)[cq];
            float4 o; o.x=a.x+b.x; o.y=a.y+b.y; o.z=a.z+b.z; o.w=a.w+b.w;
            ((float4*)bias)[ld*512 + cq] = o;
        } else if (i < 5801984L) {                // zero h ping-pong buffers (both layers)
            long j = i - 5769216L;
            uint4 z; z.x=0u; z.y=0u; z.z=0u; z.w=0u;
            ((uint4*)hbufz)[j] = z;
        } else {                                  // flags = -1 (512 flags, stride 32 ints)
            long j = i - 5801984L;
            flags[j*32] = -1;
        }
    }
}

// ---------------- xg GEMM: xg[dir] = A @ W^T, fp16 out (NO bias) ----------------
// A: [32768][Din] fp16 row-major. W: [2048][Din] fp16 (row = gate col, B^T layout).
__global__ __launch_bounds__(256) void gemm_xg(
    const unsigned short* __restrict__ A,
    const unsigned short* __restrict__ Wf,
    const unsigned short* __restrict__ Wb,
    unsigned short* __restrict__ xg,
    int Din)
{
    __shared__ __align__(16) unsigned short As[4096];   // 128 rows x 32 k, fp16
    __shared__ __align__(16) unsigned short Bs[4096];
    const int dir = blockIdx.z;
    const unsigned short* W = dir ? Wb : Wf;
    unsigned short* out = xg + (size_t)dir * 32768 * 2048;
    const int bn = blockIdx.x, bm = blockIdx.y;
    const int tid = threadIdx.x;
    const int wave = tid >> 6, lane = tid & 63;
    const int q = lane >> 4, ln = lane & 15;
    const int wm = wave >> 1, wn = wave & 1;

    f32x4 acc[4][4];
#pragma unroll
    for (int a = 0; a < 4; ++a)
#pragma unroll
        for (int b = 0; b < 4; ++b) acc[a][b] = (f32x4){0.f, 0.f, 0.f, 0.f};

    const int kiter = Din >> 5;
    for (int kb = 0; kb < kiter; ++kb) {
        __syncthreads();
#pragma unroll
        for (int i = 0; i < 2; ++i) {
            int off = i*4096 + wave*1024 + lane*16;   // byte offset in 8KB tile
            int row = off >> 6;
            int kel = (off & 63) >> 1;
            const unsigned short* sa = A + (size_t)(bm*128 + row)*Din + kb*32 + kel;
            const unsigned short* sb = W + (size_t)(bn*128 + row)*Din + kb*32 + kel;
            __builtin_amdgcn_global_load_lds(
                (const __attribute__((address_space(1))) uint32_t*)sa,
                (__attribute__((address_space(3))) uint32_t*)((char*)As + i*4096 + wave*1024),
                16, 0, 0);
            __builtin_amdgcn_global_load_lds(
                (const __attribute__((address_space(1))) uint32_t*)sb,
                (__attribute__((address_space(3))) uint32_t*)((char*)Bs + i*4096 + wave*1024),
                16, 0, 0);
        }
        __syncthreads();
        half8 af[4], bf[4];
#pragma unroll
        for (int mt = 0; mt < 4; ++mt)
            af[mt] = *(const half8*)((const char*)As + (wm*64 + mt*16 + ln)*64 + q*16);
#pragma unroll
        for (int nt = 0; nt < 4; ++nt)
            bf[nt] = *(const half8*)((const char*)Bs + (wn*64 + nt*16 + ln)*64 + q*16);
#pragma unroll
        for (int mt = 0; mt < 4; ++mt)
#pragma unroll
            for (int nt = 0; nt < 4; ++nt)
                acc[mt][nt] = __builtin_amdgcn_mfma_f32_16x16x32_f16(af[mt], bf[nt], acc[mt][nt], 0, 0, 0);
    }
#pragma unroll
    for (int mt = 0; mt < 4; ++mt)
#pragma unroll
        for (int nt = 0; nt < 4; ++nt) {
            int col = bn*128 + wn*64 + nt*16 + ln;
#pragma unroll
            for (int r = 0; r < 4; ++r) {
                int row = bm*128 + wm*64 + mt*16 + q*4 + r;
                out[(size_t)row*2048 + col] = f2h(acc[mt][nt][r]);
            }
        }
}

// ---------------- recurrent kernel: one layer, both directions ----------------
// 256 WGs x 64 threads. WG = agent (dir, g=hcol/16, bh=batch/16).
// W_hh slice lives in LDS (64KB, pre-swizzled to exact b-frag order).
__global__ __launch_bounds__(64) void rec_kernel(
    const unsigned short* __restrict__ xg,    // [2][32768][2048] fp16, bias-free
    const float* __restrict__ whhf,           // [2048][512] fp32
    const float* __restrict__ whhb,
    const float* __restrict__ bias,           // [2 dir][2048] fp32 (b_ih+b_hh)
    unsigned short* __restrict__ hbuf,        // [2 parity][2 dir][64][512] fp16
    int* __restrict__ flags,                  // flag[(dir*4+bh)*32+g] at *32 ints
    unsigned short* __restrict__ outh,        // layer0: in1 [T][64][1024] fp16
    float* __restrict__ outf,                 // layer1: d_out fp32
    const int layer)
{
    __shared__ __align__(16) unsigned short whh[32768];  // 64 KB
    const int bx = blockIdx.x;
    const int dir = bx & 1, g = (bx >> 1) & 31, bh = bx >> 6;
    const int lane = threadIdx.x;
    const int q = lane >> 4, ln = lane & 15;
    const float* whhg = dir ? whhb : whhf;

    // Preload W_hh rows {gate*512 + g*16 + r} for gate 0..3, swizzled so that at
    // read time lane's b-frag sits at base(gate,kk) + lane*16 (stride-1, no conflicts).
    {
        const int kkw = lane >> 2, qqw = lane & 3;
#pragma unroll 4
        for (int Lr = 0; Lr < 64; ++Lr) {
            int gate = Lr >> 4, r16 = Lr & 15;
            const float* src = whhg + (size_t)(gate*512 + g*16 + r16) * 512 + lane*8;
            float4 v0 = *(const float4*)src;
            float4 v1 = *(const float4*)(src + 4);
            union { unsigned short u[8]; half8 v; } p;
            p.u[0]=f2h(v0.x); p.u[1]=f2h(v0.y); p.u[2]=f2h(v0.z); p.u[3]=f2h(v0.w);
            p.u[4]=f2h(v1.x); p.u[5]=f2h(v1.y); p.u[6]=f2h(v1.z); p.u[7]=f2h(v1.w);
            *(half8*)((char*)whh + gate*16384 + kkw*1024 + qqw*256 + r16*16) = p.v;
        }
    }
    __syncthreads();

    const unsigned short* xgd = xg + (size_t)dir * 32768 * 2048;
    const float* biasd = bias + dir * 2048;
    float bv0 = biasd[0*512 + g*16 + ln];
    float bv1 = biasd[1*512 + g*16 + ln];
    float bv2 = biasd[2*512 + g*16 + ln];
    float bv3 = biasd[3*512 + g*16 + ln];

    int* myflag   = flags + ((dir*4 + bh)*32 + g) * 32;
    int* pollbase = flags + ((dir*4 + bh)*32) * 32;

    float carr[4] = {0.f, 0.f, 0.f, 0.f};

#pragma unroll 1
    for (int s = 0; s < 512; ++s) {
        const int t = dir ? (511 - s) : s;

        // xg prefetch (independent of flags -> overlaps the poll)
        unsigned short xv[4][4];
#pragma unroll
        for (int nt = 0; nt < 4; ++nt)
#pragma unroll
            for (int r = 0; r < 4; ++r)
                xv[nt][r] = xgd[(size_t)(t*64 + bh*16 + q*4 + r)*2048 + nt*512 + g*16 + ln];

        if (s > 0) {
            const int target = s - 1;
            int spins = 0;
            bool ok;
            do {
                int fv = (lane < 32)
                    ? __hip_atomic_load(pollbase + lane*32, __ATOMIC_ACQUIRE, __HIP_MEMORY_SCOPE_AGENT)
                    : 0x7fffffff;
                ok = (__ballot(fv >= target) == 0xFFFFFFFFFFFFFFFFULL);
            } while (!ok && (++spins < (1 << 15)));   // bounded spin: no hangs
        }

        const unsigned short* hread = hbuf
            + (size_t)((((s & 1) ^ 1) * 2 + dir) * 64) * 512
            + (size_t)(bh*16 + ln) * 512;

        f32x4 a0 = {0,0,0,0}, a1 = {0,0,0,0}, a2 = {0,0,0,0}, a3 = {0,0,0,0};
#pragma unroll
        for (int kk = 0; kk < 16; ++kk) {
            half8 af = *(const half8*)(hread + kk*32 + q*8);
            const char* wb = (const char*)whh + kk*1024 + lane*16;
            half8 b0 = *(const half8*)(wb);
            half8 b1 = *(const half8*)(wb + 16384);
            half8 b2 = *(const half8*)(wb + 32768);
            half8 b3 = *(const half8*)(wb + 49152);
            a0 = __builtin_amdgcn_mfma_f32_16x16x32_f16(af, b0, a0, 0, 0, 0);
            a1 = __builtin_amdgcn_mfma_f32_16x16x32_f16(af, b1, a1, 0, 0, 0);
            a2 = __builtin_amdgcn_mfma_f32_16x16x32_f16(af, b2, a2, 0, 0, 0);
            a3 = __builtin_amdgcn_mfma_f32_16x16x32_f16(af, b3, a3, 0, 0, 0);
        }

        unsigned short hs[4];
        float hv[4];
#pragma unroll
        for (int r = 0; r < 4; ++r) {
            float gi = a0[r] + h2f(xv[0][r]) + bv0;
            float gf = a1[r] + h2f(xv[1][r]) + bv1;
            float gg = a2[r] + h2f(xv[2][r]) + bv2;
            float go = a3[r] + h2f(xv[3][r]) + bv3;
            float si = 1.f / (1.f + __expf(-gi));
            float sf = 1.f / (1.f + __expf(-gf));
            float so = 1.f / (1.f + __expf(-go));
            float tg = 2.f / (1.f + __expf(-2.f*gg)) - 1.f;
            float c  = sf * carr[r] + si * tg;
            carr[r] = c;
            float th = 2.f / (1.f + __expf(-2.f*c)) - 1.f;
            hv[r] = so * th;
            hs[r] = f2h(hv[r]);
        }

        unsigned short* hwrite = hbuf + (size_t)(((s & 1) * 2 + dir) * 64) * 512;
#pragma unroll
        for (int r = 0; r < 4; ++r) {
            int row = bh*16 + q*4 + r;
            hwrite[(size_t)row*512 + g*16 + ln] = hs[r];
            if (layer == 0)
                outh[(size_t)(t*64 + row)*1024 + dir*512 + g*16 + ln] = hs[r];
            else
                outf[(size_t)(t*64 + row)*1024 + dir*512 + g*16 + ln] = hv[r];
        }
        __threadfence();
        if (lane == 0)
            __hip_atomic_store(myflag, s, __ATOMIC_RELEASE, __HIP_MEMORY_SCOPE_AGENT);
    }
}

extern "C" void kernel_launch(void* const* d_in, const int* in_sizes, int n_in,
                              void* d_out, int out_size, void* d_ws, size_t ws_size,
                              hipStream_t stream)
{
    (void)in_sizes; (void)n_in; (void)out_size; (void)ws_size;
    const float* x       = (const float*)d_in[0];
    const float* w_ih0_f = (const float*)d_in[1];
    const float* w_hh0_f = (const float*)d_in[2];
    const float* b_ih0_f = (const float*)d_in[3];
    const float* b_hh0_f = (const float*)d_in[4];
    const float* w_ih0_b = (const float*)d_in[5];
    const float* w_hh0_b = (const float*)d_in[6];
    const float* b_ih0_b = (const float*)d_in[7];
    const float* b_hh0_b = (const float*)d_in[8];
    const float* w_ih1_f = (const float*)d_in[9];
    const float* w_hh1_f = (const float*)d_in[10];
    const float* b_ih1_f = (const float*)d_in[11];
    const float* b_hh1_f = (const float*)d_in[12];
    const float* w_ih1_b = (const float*)d_in[13];
    const float* w_hh1_b = (const float*)d_in[14];
    const float* b_ih1_b = (const float*)d_in[15];
    const float* b_hh1_b = (const float*)d_in[16];

    // workspace layout (bytes): xg 256MB | wih_h 12MB | bias 32KB | hbuf 512KB | flags 64KB
    char* ws = (char*)d_ws;
    unsigned short* xg    = (unsigned short*)(ws + 0);
    unsigned short* wihh  = (unsigned short*)(ws + 268435456L);
    float*          bias  = (float*)         (ws + 281018368L);
    unsigned short* hbuf  = (unsigned short*)(ws + 281051136L);
    int*            flags = (int*)           (ws + 281575424L);

    // scratch stashed inside d_out (consumed before final output is written):
    unsigned short* in1 = (unsigned short*)d_out;                      // 67MB fp16 [T][64][1024]
    unsigned short* xh  = (unsigned short*)((char*)d_out + 67108864L); // 33.5MB fp16 x
    float* outf = (float*)d_out;

    prep_kernel<<<dim3(1024), dim3(256), 0, stream>>>(
        x, w_ih0_f, w_ih0_b, w_ih1_f, w_ih1_b,
        b_ih0_f, b_hh0_f, b_ih0_b, b_hh0_b,
        b_ih1_f, b_hh1_f, b_ih1_b, b_hh1_b,
        xh, wihh, bias, (uint32_t*)hbuf, flags);

    // layer 0
    gemm_xg<<<dim3(16, 256, 2), dim3(256), 0, stream>>>(
        xh, wihh, wihh + 1048576, xg, 512);
    rec_kernel<<<dim3(256), dim3(64), 0, stream>>>(
        xg, w_hh0_f, w_hh0_b, bias, hbuf, flags, in1, (float*)nullptr, 0);

    // layer 1
    gemm_xg<<<dim3(16, 256, 2), dim3(256), 0, stream>>>(
        in1, wihh + 2097152, wihh + 4194304, xg, 1024);
    rec_kernel<<<dim3(256), dim3(64), 0, stream>>>(
        xg, w_hh1_f, w_hh1_b, bias + 4096, hbuf + 131072, flags + 8192,
        (unsigned short*)nullptr, outf, 1);
}

// Round 3
// 7310.555 us; speedup vs baseline: 2.8102x; 2.8102x over previous
//
#include <hip/hip_runtime.h>
#include <hip/hip_bf16.h>
#include <stdint.h>

// LSTM bidirectional 2-layer, T=512 B=64 D=H=512.
// prep(cast+bias+init) -> gemm_xg(L0) -> rec(L0) -> gemm_xg(L1) -> rec(L1).
// rec: 256 single-wave WGs, flag-synced per step (batch-independent groups of 32).
// R3: ALL cross-WG communication via RELAXED agent-scope atomics (sc0/sc1 -> L3
//     coherent point). No acquire/release -> no buffer_inv/buffer_wbl2 L2 nukes
//     (R2's 19.7us/step + 692MB refetch pathology). xg stored transposed
//     [t][gate][hcol][brow] so rec prefetch is 4x8B loads.

typedef __attribute__((ext_vector_type(8))) _Float16 half8;
typedef __attribute__((ext_vector_type(4))) float f32x4;
typedef unsigned long long ull;

__device__ __forceinline__ unsigned short f2h(float f) {
    union { _Float16 h; unsigned short u; } c; c.h = (_Float16)f; return c.u;
}
__device__ __forceinline__ float h2f(unsigned short u) {
    union { _Float16 h; unsigned short u; } c; c.u = u; return (float)c.h;
}

// ---------------- prep: casts, bias sums, state init ----------------
__global__ __launch_bounds__(256) void prep_kernel(
    const float* __restrict__ x,
    const float* __restrict__ w0f, const float* __restrict__ w0b,
    const float* __restrict__ w1f, const float* __restrict__ w1b,
    const float* __restrict__ bi0f, const float* __restrict__ bh0f,
    const float* __restrict__ bi0b, const float* __restrict__ bh0b,
    const float* __restrict__ bi1f, const float* __restrict__ bh1f,
    const float* __restrict__ bi1b, const float* __restrict__ bh1b,
    unsigned short* __restrict__ xh,
    unsigned short* __restrict__ wihh,
    float* __restrict__ bias,
    uint32_t* __restrict__ hbufz,
    int* __restrict__ flags)
{
    const long total = 5802496L;   // units of 16B quads (mostly)
    long stride = (long)gridDim.x * blockDim.x;
    for (long i = (long)blockIdx.x * blockDim.x + threadIdx.x; i < total; i += stride) {
        if (i < 4194304L) {                       // x: fp32 -> fp16 (16.78M elems)
            float4 v = ((const float4*)x)[i];
            ushort4 o; o.x=f2h(v.x); o.y=f2h(v.y); o.z=f2h(v.z); o.w=f2h(v.w);
            ((ushort4*)xh)[i] = o;
        } else if (i < 5767168L) {                // w_ih casts: [w0f][w0b][w1f][w1b]
            long j = i - 4194304L;
            const float* src; long sq;
            if (j < 262144L)       { src = w0f; sq = j;            }
            else if (j < 524288L)  { src = w0b; sq = j - 262144L;  }
            else if (j < 1048576L) { src = w1f; sq = j - 524288L;  }
            else                   { src = w1b; sq = j - 1048576L; }
            float4 v = ((const float4*)src)[sq];
            ushort4 o; o.x=f2h(v.x); o.y=f2h(v.y); o.z=f2h(v.z); o.w=f2h(v.w);
            ((ushort4*)wihh)[j] = o;
        } else if (i < 5769216L) {                // bias sums: b_ih + b_hh, 4 x 2048 fp32
            long j = i - 5767168L;                // 0..2047 quads
            int ld = (int)(j >> 9);
            long cq = j & 511L;
            const float* bi = ld==0?bi0f: ld==1?bi0b: ld==2?bi1f:bi1b;
            const float* bh = ld==0?bh0f: ld==1?bh0b: ld==2?bh1f:bh1b;
            float4 a = ((const float4*)bi)[cq];
            float4 b = ((const float4*)bh)[cq];
            float4 o; o.x=a.x+b.x; o.y=a.y+b.y; o.z=a.z+b.z; o.w=a.w+b.w;
            ((float4*)bias)[ld*512 + cq] = o;
        } else if (i < 5801984L) {                // zero h ping-pong buffers (both layers)
            long j = i - 5769216L;
            uint4 z; z.x=0u; z.y=0u; z.z=0u; z.w=0u;
            ((uint4*)hbufz)[j] = z;
        } else {                                  // flags = -1 (512 flags, stride 32 ints)
            long j = i - 5801984L;
            flags[j*32] = -1;
        }
    }
}

// ---------------- xg GEMM: xg = A @ W^T, fp16 out, TRANSPOSED layout ----------------
// A: [32768][Din] fp16 row-major (rows = t*64+b). W: [2048][Din] fp16 (B^T layout).
// out[dir]: [t 512][gate 4][hcol 512][brow 64] fp16.
__global__ __launch_bounds__(256) void gemm_xg(
    const unsigned short* __restrict__ A,
    const unsigned short* __restrict__ Wf,
    const unsigned short* __restrict__ Wb,
    unsigned short* __restrict__ xg,
    int Din)
{
    __shared__ __align__(16) unsigned short As[4096];   // 128 rows x 32 k, fp16
    __shared__ __align__(16) unsigned short Bs[4096];
    const int dir = blockIdx.z;
    const unsigned short* W = dir ? Wb : Wf;
    unsigned short* out = xg + (size_t)dir * 32768 * 2048;
    const int bn = blockIdx.x, bm = blockIdx.y;
    const int tid = threadIdx.x;
    const int wave = tid >> 6, lane = tid & 63;
    const int q = lane >> 4, ln = lane & 15;
    const int wm = wave >> 1, wn = wave & 1;

    f32x4 acc[4][4];
#pragma unroll
    for (int a = 0; a < 4; ++a)
#pragma unroll
        for (int b = 0; b < 4; ++b) acc[a][b] = (f32x4){0.f, 0.f, 0.f, 0.f};

    const int kiter = Din >> 5;
    for (int kb = 0; kb < kiter; ++kb) {
        __syncthreads();
#pragma unroll
        for (int i = 0; i < 2; ++i) {
            int off = i*4096 + wave*1024 + lane*16;   // byte offset in 8KB tile
            int row = off >> 6;
            int kel = (off & 63) >> 1;
            const unsigned short* sa = A + (size_t)(bm*128 + row)*Din + kb*32 + kel;
            const unsigned short* sb = W + (size_t)(bn*128 + row)*Din + kb*32 + kel;
            __builtin_amdgcn_global_load_lds(
                (const __attribute__((address_space(1))) uint32_t*)sa,
                (__attribute__((address_space(3))) uint32_t*)((char*)As + i*4096 + wave*1024),
                16, 0, 0);
            __builtin_amdgcn_global_load_lds(
                (const __attribute__((address_space(1))) uint32_t*)sb,
                (__attribute__((address_space(3))) uint32_t*)((char*)Bs + i*4096 + wave*1024),
                16, 0, 0);
        }
        __syncthreads();
        half8 af[4], bf[4];
#pragma unroll
        for (int mt = 0; mt < 4; ++mt)
            af[mt] = *(const half8*)((const char*)As + (wm*64 + mt*16 + ln)*64 + q*16);
#pragma unroll
        for (int nt = 0; nt < 4; ++nt)
            bf[nt] = *(const half8*)((const char*)Bs + (wn*64 + nt*16 + ln)*64 + q*16);
#pragma unroll
        for (int mt = 0; mt < 4; ++mt)
#pragma unroll
            for (int nt = 0; nt < 4; ++nt)
                acc[mt][nt] = __builtin_amdgcn_mfma_f32_16x16x32_f16(af[mt], bf[nt], acc[mt][nt], 0, 0, 0);
    }
    // epilogue: transposed store. tile row = t*64 + brow with t = bm*2+wm (128 rows = 2 t).
    const int tt = bm*2 + wm;
#pragma unroll
    for (int mt = 0; mt < 4; ++mt)
#pragma unroll
        for (int nt = 0; nt < 4; ++nt) {
            int col = bn*128 + wn*64 + nt*16 + ln;
            int gate = col >> 9, colg = col & 511;
            union { unsigned short u[4]; ull v; } p;
#pragma unroll
            for (int r = 0; r < 4; ++r) p.u[r] = f2h(acc[mt][nt][r]);
            *(ull*)(out + (((size_t)tt*4 + gate)*512 + colg)*64 + mt*16 + q*4) = p.v;
        }
}

// ---------------- recurrent kernel: one layer, both directions ----------------
// 256 WGs x 64 threads. WG = agent (dir, g=hcol/16, bh=batch/16).
// W_hh slice in LDS (64KB, pre-swizzled). h exchange: relaxed agent atomics (L3).
__global__ __launch_bounds__(64) void rec_kernel(
    const unsigned short* __restrict__ xg,    // [dir][t][gate][hcol][brow] fp16, bias-free
    const float* __restrict__ whhf,           // [2048][512] fp32
    const float* __restrict__ whhb,
    const float* __restrict__ bias,           // [2 dir][2048] fp32 (b_ih+b_hh)
    unsigned short* __restrict__ hbuf,        // [2 parity][2 dir][64][512] fp16
    int* __restrict__ flags,                  // flag[(dir*4+bh)*32+g] at *32 ints
    unsigned short* __restrict__ outh,        // layer0: in1 [T][64][1024] fp16
    float* __restrict__ outf,                 // layer1: d_out fp32
    const int layer)
{
    __shared__ __align__(16) unsigned short whh[32768];  // 64 KB
    __shared__ __align__(16) unsigned short htile[256];  // 512 B repack scratch
    const int bx = blockIdx.x;
    const int dir = bx & 1, g = (bx >> 1) & 31, bh = bx >> 6;
    const int lane = threadIdx.x;
    const int q = lane >> 4, ln = lane & 15;
    const float* whhg = dir ? whhb : whhf;

    // Preload W_hh rows {gate*512 + g*16 + r}, swizzled so lane's b-frag sits at
    // base(gate,kk) + lane*16 (stride-1, conflict-free ds_read_b128).
    {
        const int kkw = lane >> 2, qqw = lane & 3;
#pragma unroll 4
        for (int Lr = 0; Lr < 64; ++Lr) {
            int gate = Lr >> 4, r16 = Lr & 15;
            const float* src = whhg + (size_t)(gate*512 + g*16 + r16) * 512 + lane*8;
            float4 v0 = *(const float4*)src;
            float4 v1 = *(const float4*)(src + 4);
            union { unsigned short u[8]; half8 v; } p;
            p.u[0]=f2h(v0.x); p.u[1]=f2h(v0.y); p.u[2]=f2h(v0.z); p.u[3]=f2h(v0.w);
            p.u[4]=f2h(v1.x); p.u[5]=f2h(v1.y); p.u[6]=f2h(v1.z); p.u[7]=f2h(v1.w);
            *(half8*)((char*)whh + gate*16384 + kkw*1024 + qqw*256 + r16*16) = p.v;
        }
    }
    __syncthreads();

    const unsigned short* xgd = xg + (size_t)dir * 32768 * 2048;
    const float* biasd = bias + dir * 2048;
    float bv0 = biasd[0*512 + g*16 + ln];
    float bv1 = biasd[1*512 + g*16 + ln];
    float bv2 = biasd[2*512 + g*16 + ln];
    float bv3 = biasd[3*512 + g*16 + ln];

    int* myflag   = flags + ((dir*4 + bh)*32 + g) * 32;
    int* pollbase = flags + ((dir*4 + bh)*32) * 32;

    float carr[4] = {0.f, 0.f, 0.f, 0.f};

#pragma unroll 1
    for (int s = 0; s < 512; ++s) {
        const int t = dir ? (511 - s) : s;

        // xg prefetch: 4 x 8B normal (cacheable) loads; overlaps the poll.
        ull xv64[4];
#pragma unroll
        for (int nt = 0; nt < 4; ++nt)
            xv64[nt] = *(const ull*)(xgd + ((size_t)(t*4 + nt)*512 + g*16 + ln)*64 + bh*16 + q*4);

        if (s > 0) {
            const int target = s - 1;
            int spins = 0;
            bool ok;
            do {
                int fv = (lane < 32)
                    ? __hip_atomic_load(pollbase + lane*32, __ATOMIC_RELAXED, __HIP_MEMORY_SCOPE_AGENT)
                    : 0x7fffffff;
                ok = (__ballot(fv >= target) == 0xFFFFFFFFFFFFFFFFULL);
            } while (!ok && (++spins < (1 << 18)));   // bounded spin: no hangs
            asm volatile("" ::: "memory");            // keep h loads below the poll
        }

        // h_{t-1} read: relaxed agent atomics (sc0 sc1 -> L3, no cache invalidates)
        const ull* hread = (const ull*)(hbuf
            + (size_t)((((s & 1) ^ 1) * 2 + dir) * 64 + bh*16 + ln) * 512);

        f32x4 a0 = {0,0,0,0}, a1 = {0,0,0,0}, a2 = {0,0,0,0}, a3 = {0,0,0,0};
#pragma unroll
        for (int kk = 0; kk < 16; ++kk) {
            ull lo = __hip_atomic_load(hread + kk*8 + q*2,     __ATOMIC_RELAXED, __HIP_MEMORY_SCOPE_AGENT);
            ull hi = __hip_atomic_load(hread + kk*8 + q*2 + 1, __ATOMIC_RELAXED, __HIP_MEMORY_SCOPE_AGENT);
            union { ull u[2]; half8 v; } afu; afu.u[0] = lo; afu.u[1] = hi;
            const char* wb = (const char*)whh + kk*1024 + lane*16;
            half8 b0 = *(const half8*)(wb);
            half8 b1 = *(const half8*)(wb + 16384);
            half8 b2 = *(const half8*)(wb + 32768);
            half8 b3 = *(const half8*)(wb + 49152);
            a0 = __builtin_amdgcn_mfma_f32_16x16x32_f16(afu.v, b0, a0, 0, 0, 0);
            a1 = __builtin_amdgcn_mfma_f32_16x16x32_f16(afu.v, b1, a1, 0, 0, 0);
            a2 = __builtin_amdgcn_mfma_f32_16x16x32_f16(afu.v, b2, a2, 0, 0, 0);
            a3 = __builtin_amdgcn_mfma_f32_16x16x32_f16(afu.v, b3, a3, 0, 0, 0);
        }

        unsigned short hs[4];
#pragma unroll
        for (int r = 0; r < 4; ++r) {
            float gi = a0[r] + h2f((unsigned short)(xv64[0] >> (16*r))) + bv0;
            float gf = a1[r] + h2f((unsigned short)(xv64[1] >> (16*r))) + bv1;
            float gg = a2[r] + h2f((unsigned short)(xv64[2] >> (16*r))) + bv2;
            float go = a3[r] + h2f((unsigned short)(xv64[3] >> (16*r))) + bv3;
            float si = 1.f / (1.f + __expf(-gi));
            float sf = 1.f / (1.f + __expf(-gf));
            float so = 1.f / (1.f + __expf(-go));
            float tg = 2.f / (1.f + __expf(-2.f*gg)) - 1.f;
            float c  = sf * carr[r] + si * tg;
            carr[r] = c;
            float th = 2.f / (1.f + __expf(-2.f*c)) - 1.f;
            hs[r] = f2h(so * th);
        }

        // repack 16x16 tile via LDS so each lane holds 8B contiguous (row, 4 cols)
#pragma unroll
        for (int r = 0; r < 4; ++r) htile[(q*4 + r)*16 + ln] = hs[r];
        __syncthreads();
        ull hv64 = *(const ull*)(htile + (lane >> 2)*16 + (lane & 3)*4);
        const int row  = bh*16 + (lane >> 2);
        const int colw = g*16 + (lane & 3)*4;

        unsigned short* hwrite = hbuf + (size_t)(((s & 1) * 2 + dir) * 64) * 512;
        __hip_atomic_store((ull*)(hwrite + (size_t)row*512 + colw), hv64,
                           __ATOMIC_RELAXED, __HIP_MEMORY_SCOPE_AGENT);

        if (layer == 0) {
            *(ull*)(outh + (size_t)(t*64 + row)*1024 + dir*512 + colw) = hv64;
        } else {
            union { ull u; unsigned short us[4]; } pu; pu.u = hv64;
            float4 o; o.x = h2f(pu.us[0]); o.y = h2f(pu.us[1]);
            o.z = h2f(pu.us[2]); o.w = h2f(pu.us[3]);
            *(float4*)(outf + (size_t)(t*64 + row)*1024 + dir*512 + colw) = o;
        }

        asm volatile("s_waitcnt vmcnt(0)" ::: "memory");   // h stores globally visible
        if (lane == 0)
            __hip_atomic_store(myflag, s, __ATOMIC_RELAXED, __HIP_MEMORY_SCOPE_AGENT);
        __syncthreads();   // htile reuse guard
    }
}

extern "C" void kernel_launch(void* const* d_in, const int* in_sizes, int n_in,
                              void* d_out, int out_size, void* d_ws, size_t ws_size,
                              hipStream_t stream)
{
    (void)in_sizes; (void)n_in; (void)out_size; (void)ws_size;
    const float* x       = (const float*)d_in[0];
    const float* w_ih0_f = (const float*)d_in[1];
    const float* w_hh0_f = (const float*)d_in[2];
    const float* b_ih0_f = (const float*)d_in[3];
    const float* b_hh0_f = (const float*)d_in[4];
    const float* w_ih0_b = (const float*)d_in[5];
    const float* w_hh0_b = (const float*)d_in[6];
    const float* b_ih0_b = (const float*)d_in[7];
    const float* b_hh0_b = (const float*)d_in[8];
    const float* w_ih1_f = (const float*)d_in[9];
    const float* w_hh1_f = (const float*)d_in[10];
    const float* b_ih1_f = (const float*)d_in[11];
    const float* b_hh1_f = (const float*)d_in[12];
    const float* w_ih1_b = (const float*)d_in[13];
    const float* w_hh1_b = (const float*)d_in[14];
    const float* b_ih1_b = (const float*)d_in[15];
    const float* b_hh1_b = (const float*)d_in[16];

    // workspace layout (bytes): xg 256MB | wih_h 12MB | bias 32KB | hbuf 512KB | flags 64KB
    char* ws = (char*)d_ws;
    unsigned short* xg    = (unsigned short*)(ws + 0);
    unsigned short* wihh  = (unsigned short*)(ws + 268435456L);
    float*          bias  = (float*)         (ws + 281018368L);
    unsigned short* hbuf  = (unsigned short*)(ws + 281051136L);
    int*            flags = (int*)           (ws + 281575424L);

    // scratch stashed inside d_out (consumed before final output is written):
    unsigned short* in1 = (unsigned short*)d_out;                      // 67MB fp16 [T][64][1024]
    unsigned short* xh  = (unsigned short*)((char*)d_out + 67108864L); // 33.5MB fp16 x
    float* outf = (float*)d_out;

    prep_kernel<<<dim3(1024), dim3(256), 0, stream>>>(
        x, w_ih0_f, w_ih0_b, w_ih1_f, w_ih1_b,
        b_ih0_f, b_hh0_f, b_ih0_b, b_hh0_b,
        b_ih1_f, b_hh1_f, b_ih1_b, b_hh1_b,
        xh, wihh, bias, (uint32_t*)hbuf, flags);

    // layer 0
    gemm_xg<<<dim3(16, 256, 2), dim3(256), 0, stream>>>(
        xh, wihh, wihh + 1048576, xg, 512);
    rec_kernel<<<dim3(256), dim3(64), 0, stream>>>(
        xg, w_hh0_f, w_hh0_b, bias, hbuf, flags, in1, (float*)nullptr, 0);

    // layer 1
    gemm_xg<<<dim3(16, 256, 2), dim3(256), 0, stream>>>(
        in1, wihh + 2097152, wihh + 4194304, xg, 1024);
    rec_kernel<<<dim3(256), dim3(64), 0, stream>>>(
        xg, w_hh1_f, w_hh1_b, bias + 4096, hbuf + 131072, flags + 8192,
        (unsigned short*)nullptr, outf, 1);
}